// Round 5
// baseline (113.461 us; speedup 1.0000x reference)
//
#include <hip/hip_runtime.h>

// LBP for semantic dependency parsing — label-difference form, all 3
// iterations fused into one kernel, state fully register-resident.
//
//   E[b,i,j,k]  = 2^(log2e*s[b,i,j,k]) - 1          (only use of the scores)
//   D_0 = 0;  D_t = log2(1+p+E) - log2(1+p),  p = 2^(D_{t-1} - q_{t-1}[i])
//   q_t[k] = q0[k] + mask[k] * sum_i D^sum_t[i,k] * mask[i]*(i!=j)*(i!=k)
//   out[b,k,j] = 1/(1+2^(-q_3[k]))
// Block (b,j) closes the whole recursion for column j. Scores are read from
// HBM exactly once; staging is fused with pass 1 so the HBM read overlaps
// the pass-1 transcendental chain. __launch_bounds__(512,2) gives the
// 256-VGPR budget the 192-register E/D payload needs (round-4 counter
// showed VGPR=112 -> massive scratch spill; that was the bottleneck).

#define TS 128
#define ROWS 8          // rows per thread (512 threads: 16 row-groups x 32 k-quads)

typedef float f4v __attribute__((ext_vector_type(4)));

constexpr float LOG2E = 1.4426950408889634f;

// ---- mask format probe: f[0]!=0 -> byte mask, f[1]!=0 -> float32, else int32
__global__ void flags_init(int* __restrict__ f) { f[0] = 0; f[1] = 0; }

__global__ void mask_detect(const unsigned char* __restrict__ m, int n, int* __restrict__ f) {
    int v1 = 0, v23 = 0;
    for (int i = blockIdx.x * blockDim.x + threadIdx.x; i < n; i += gridDim.x * blockDim.x) {
        const unsigned char b = m[i];           // first n bytes: in-bounds for all layouts
        const int r = i & 3;
        if (r == 1) v1 |= b;
        if (r >= 2) v23 |= b;
    }
    const int lane = threadIdx.x & 63;
    if (__any(v1)  && lane == 0) atomicOr(&f[0], 1);
    if (__any(v23) && lane == 0) atomicOr(&f[1], 1);
}

__global__ __launch_bounds__(512, 2)
void lbp_fused(const float* __restrict__ s_edge,
               const f4v* __restrict__ sib4,
               const f4v* __restrict__ cop4,
               const f4v* __restrict__ grd4,
               const void* __restrict__ mask,
               const int* __restrict__ flags,
               float* __restrict__ outp)
{
    __shared__ float qs[TS], q0s[TS], p1s[TS], lp1s[TS];
    __shared__ f4v red4[16 * 32];
    __shared__ unsigned char mrow[TS];

    const int bj = blockIdx.x;
    const int b  = bj >> 7;
    const int j  = bj & (TS - 1);
    const int t  = threadIdx.x;
    const int kq = t & 31;          // k-quad: k = 4*kq..4*kq+3
    const int rq = t >> 5;          // row-group 0..15
    const int i0 = rq * ROWS;
    const int k0 = kq * 4;

    // ---- per-column prologue ----
    if (t < TS) {
        const int i = t;
        const int idx = (b * TS + i) * TS + j;
        const float q0 = LOG2E * s_edge[idx];
        q0s[i] = q0;
        qs[i]  = q0;
        const int f1 = flags[0], f23 = flags[1];
        unsigned char mv;
        if (f1)       mv = ((const unsigned char*)mask)[idx] != 0;
        else if (f23) mv = ((const float*)mask)[idx] != 0.0f;
        else          mv = ((const int*)mask)[idx]   != 0;
        mrow[i] = mv;
        const float p1 = exp2f(-q0);
        p1s[i]  = p1;
        lp1s[i] = __log2f(1.0f + p1);
    }
    __syncthreads();

    // ---- fused stage + pass 1: load scores once, E and D1 into registers ----
    f4v Es[ROWS], Ec[ROWS], Eg[ROWS], Ds[ROWS], Dc[ROWS], Dg[ROWS];
    const size_t colBase4 = (size_t)b * (TS * TS * TS / 4) + (size_t)j * (TS / 4) + kq;

    f4v acc;
    acc[0] = acc[1] = acc[2] = acc[3] = 0.0f;
    #pragma unroll
    for (int r = 0; r < ROWS; ++r) {
        const int i = i0 + r;
        const size_t off = colBase4 + (size_t)i * (TS * TS / 4);
        const f4v vs = sib4[off];
        const f4v vc = cop4[off];
        const f4v vg = grd4[off];
        const bool live = (mrow[i] != 0) && (i != j);
        const float p1 = p1s[i], l1 = lp1s[i];
        #pragma unroll
        for (int c = 0; c < 4; ++c) {
            const float es = exp2f(LOG2E * vs[c]) - 1.0f;
            const float ec = exp2f(LOG2E * vc[c]) - 1.0f;
            const float eg = exp2f(LOG2E * vg[c]) - 1.0f;
            Es[r][c] = es; Ec[r][c] = ec; Eg[r][c] = eg;
            const float ds = __log2f(1.0f + p1 + es) - l1;
            const float dc = __log2f(1.0f + p1 + ec) - l1;
            const float dg = __log2f(1.0f + p1 + eg) - l1;
            Ds[r][c] = ds; Dc[r][c] = dc; Dg[r][c] = dg;
            if (live && (i != k0 + c)) acc[c] += ds + dc + dg;
        }
    }
    red4[rq * 32 + kq] = acc;
    __syncthreads();
    if (t < TS) {
        const float* red = (const float*)red4;
        float tot = 0.0f;
        #pragma unroll
        for (int g = 0; g < 16; ++g) tot += red[g * TS + t];
        qs[t] = q0s[t] + (mrow[t] ? tot : 0.0f);
    }
    __syncthreads();

    // ---- passes 2 and 3 (register-resident state) ----
    #pragma unroll
    for (int pass = 0; pass < 2; ++pass) {
        acc[0] = acc[1] = acc[2] = acc[3] = 0.0f;
        #pragma unroll
        for (int r = 0; r < ROWS; ++r) {
            const int i = i0 + r;
            const bool live = (mrow[i] != 0) && (i != j);
            if (live) {
                const float q = qs[i];
                #pragma unroll
                for (int c = 0; c < 4; ++c) {
                    float p, a, dn, s;
                    p = exp2f(fminf(Ds[r][c] - q, 126.0f));
                    a = 1.0f + p;
                    dn = __log2f(a + Es[r][c]) - __log2f(a);
                    Ds[r][c] = dn; s = dn;
                    p = exp2f(fminf(Dc[r][c] - q, 126.0f));
                    a = 1.0f + p;
                    dn = __log2f(a + Ec[r][c]) - __log2f(a);
                    Dc[r][c] = dn; s += dn;
                    p = exp2f(fminf(Dg[r][c] - q, 126.0f));
                    a = 1.0f + p;
                    dn = __log2f(a + Eg[r][c]) - __log2f(a);
                    Dg[r][c] = dn; s += dn;
                    if (i != k0 + c) acc[c] += s;
                }
            }
        }
        red4[rq * 32 + kq] = acc;
        __syncthreads();
        if (t < TS) {
            const float* red = (const float*)red4;
            float tot = 0.0f;
            #pragma unroll
            for (int g = 0; g < 16; ++g) tot += red[g * TS + t];
            qs[t] = q0s[t] + (mrow[t] ? tot : 0.0f);
        }
        __syncthreads();
    }

    if (t < TS)
        outp[(b * TS + t) * TS + j] = 1.0f / (1.0f + exp2f(-qs[t]));
}

extern "C" void kernel_launch(void* const* d_in, const int* in_sizes, int n_in,
                              void* d_out, int out_size, void* d_ws, size_t ws_size,
                              hipStream_t stream) {
    const float* s_edge = (const float*)d_in[0];
    const f4v*   sib4   = (const f4v*)d_in[1];
    const f4v*   cop4   = (const f4v*)d_in[2];
    const f4v*   grd4   = (const f4v*)d_in[3];
    const void*  mask   = d_in[4];
    float* out = (float*)d_out;

    const int Bn = in_sizes[0] / (TS * TS);   // batch
    const int nMask = in_sizes[4];            // B*S*S elements

    int* flags = (int*)d_ws;

    flags_init<<<1, 1, 0, stream>>>(flags);
    mask_detect<<<64, 256, 0, stream>>>((const unsigned char*)mask, nMask, flags);
    lbp_fused<<<Bn * TS, 512, 0, stream>>>(s_edge, sib4, cop4, grd4, mask, flags, out);
}